// Round 1
// baseline (394.047 us; speedup 1.0000x reference)
//
#include <hip/hip_runtime.h>

#define TPTS 128          // control points T
#define MM   132          // T + DIM + 1
#define NRHS 3
#define AC   135          // MM + NRHS (augmented columns)
#define ST   136          // padded row stride (float4-aligned)
#define TEPS 1e-6f

// ---------------- Fit: build bordered TPS system and solve (GEPP) -----------
// One block (256 threads) per batch. Augmented matrix lives in dynamic LDS.
__global__ __launch_bounds__(256) void tps_fit(
    const float* __restrict__ pm,   // points_m  [N][T][3] (targets)
    const float* __restrict__ pf,   // points_f  [N][T][3] (control)
    const float* __restrict__ lmb,  // lambda    [N]
    float* __restrict__ theta)      // out: [N][MM][3]; rows<T pre-scaled by ln2
{
    extern __shared__ float sm[];
    float* M  = sm;                 // [MM][ST]
    float* sc = sm + MM * ST;       // ctrl  [T][3]
    float* sg = sc + TPTS * 3;      // tgt   [T][3]
    __shared__ int s_piv;

    const int n   = blockIdx.x;
    const int tid = threadIdx.x;

    for (int i = tid; i < TPTS * 3; i += 256) {
        sc[i] = pf[n * TPTS * 3 + i];
        sg[i] = pm[n * TPTS * 3 + i];
    }
    __syncthreads();
    const float lam = lmb[n];

    // Fill augmented matrix [K P pm; P^T 0 0], pad col = 0
    for (int idx = tid; idx < MM * ST; idx += 256) {
        const int row = idx / ST;
        const int col = idx - row * ST;
        float v = 0.0f;
        if (col < TPTS) {
            if (row < TPTS) {
                const float dx = sc[row*3+0] - sc[col*3+0];
                const float dy = sc[row*3+1] - sc[col*3+1];
                const float dz = sc[row*3+2] - sc[col*3+2];
                const float r2 = fmaf(dx,dx, fmaf(dy,dy, fmaf(dz,dz, TEPS)));
                const float r  = sqrtf(r2);
                v = r2 * logf(r + TEPS);        // matches U(pairdist): diag = U(sqrt(EPS))
                if (row == col) v += lam;
            } else {
                const int ci = row - TPTS;      // P^T block
                v = (ci == 0) ? 1.0f : sc[col*3 + ci - 1];
            }
        } else if (col < MM) {
            if (row < TPTS) {                   // P block
                const int ci = col - TPTS;
                v = (ci == 0) ? 1.0f : sc[row*3 + ci - 1];
            }
        } else if (col < AC) {
            if (row < TPTS) v = sg[row*3 + (col - MM)];  // RHS
        }
        M[idx] = v;
    }
    __syncthreads();

    const int tx = tid & 31;
    const int ty = tid >> 5;

    // Forward elimination with partial pivoting
    for (int j = 0; j < MM; ++j) {
        if (tid < 64) {                          // wave-0 pivot search
            float bv = -1.0f; int bi = j;
            for (int i = j + tid; i < MM; i += 64) {
                const float v = fabsf(M[i*ST + j]);
                if (v > bv) { bv = v; bi = i; }
            }
            #pragma unroll
            for (int off = 32; off; off >>= 1) {
                const float ov = __shfl_down(bv, off);
                const int   oi = __shfl_down(bi, off);
                if (ov > bv) { bv = ov; bi = oi; }
            }
            if (tid == 0) s_piv = bi;
        }
        __syncthreads();
        const int piv = s_piv;
        if (piv != j) {                          // uniform branch
            for (int c = j + tid; c < AC; c += 256) {
                const float a = M[j*ST + c];
                M[j*ST + c]   = M[piv*ST + c];
                M[piv*ST + c] = a;
            }
            __syncthreads();
        }
        const float pivinv = 1.0f / M[j*ST + j];
        const int cb  = j >> 2;                  // float4 block covering col j
        const int c40 = cb + tx;
        const int c41 = c40 + 32;
        const float4* Mj4 = reinterpret_cast<const float4*>(M + j*ST);
        float4 pv0 = make_float4(0.f,0.f,0.f,0.f);
        float4 pv1 = make_float4(0.f,0.f,0.f,0.f);
        if (c40 < ST/4) pv0 = Mj4[c40];
        if (c41 < ST/4) pv1 = Mj4[c41];
        // each row owned by exactly one wave half -> f-read precedes writes in lockstep
        for (int i = j + 1 + ty; i < MM; i += 8) {
            const float f = M[i*ST + j] * pivinv;
            float4* Mi4 = reinterpret_cast<float4*>(M + i*ST);
            if (c40 < ST/4) {
                float4 m = Mi4[c40];
                m.x = fmaf(-f, pv0.x, m.x); m.y = fmaf(-f, pv0.y, m.y);
                m.z = fmaf(-f, pv0.z, m.z); m.w = fmaf(-f, pv0.w, m.w);
                Mi4[c40] = m;
            }
            if (c41 < ST/4) {
                float4 m = Mi4[c41];
                m.x = fmaf(-f, pv1.x, m.x); m.y = fmaf(-f, pv1.y, m.y);
                m.z = fmaf(-f, pv1.z, m.z); m.w = fmaf(-f, pv1.w, m.w);
                Mi4[c41] = m;
            }
        }
        __syncthreads();
    }

    // Backward substitution on the 3 RHS columns
    for (int j = MM - 1; j >= 0; --j) {
        if (tid == 0) {
            const float d = 1.0f / M[j*ST + j];
            M[j*ST + MM+0] *= d;
            M[j*ST + MM+1] *= d;
            M[j*ST + MM+2] *= d;
        }
        __syncthreads();
        const float x0 = M[j*ST + MM+0];
        const float x1 = M[j*ST + MM+1];
        const float x2 = M[j*ST + MM+2];
        for (int i = tid; i < j; i += 256) {
            const float u = M[i*ST + j];
            M[i*ST + MM+0] = fmaf(-u, x0, M[i*ST + MM+0]);
            M[i*ST + MM+1] = fmaf(-u, x1, M[i*ST + MM+1]);
            M[i*ST + MM+2] = fmaf(-u, x2, M[i*ST + MM+2]);
        }
        __syncthreads();
    }

    // Emit theta; fold ln2 into TPS weights so eval can use raw log2
    for (int idx = tid; idx < MM * 3; idx += 256) {
        const int row = idx / 3;
        float v = M[row*ST + MM + (idx - row*3)];
        if (row < TPTS) v *= 0.6931471805599453f;
        theta[n*MM*3 + idx] = v;
    }
}

// ---------------- Eval: z = U(r)·w + g·a over the 64^3 grid ----------------
__global__ __launch_bounds__(256) void tps_eval(
    const float* __restrict__ pf,     // control points [N][T][3]
    const float* __restrict__ theta,  // [N][MM][3]
    float* __restrict__ out)          // [N][D][H][W][3]
{
    const int b   = blockIdx.x;
    const int n   = b >> 10;                       // 1024 blocks per batch (uniform!)
    const int rem = ((b & 1023) << 8) | threadIdx.x;
    const int d = rem >> 12;
    const int h = (rem >> 6) & 63;
    const int w = rem & 63;
    const float stepv = 2.0f / 63.0f;
    const float gx = fmaf((float)w, stepv, -1.0f);  // c1 along W
    const float gy = fmaf((float)h, stepv, -1.0f);  // c2 along H
    const float gz = fmaf((float)d, stepv, -1.0f);  // c3 along D

    const float* __restrict__ c  = pf    + n * TPTS * 3;  // block-uniform -> s_load
    const float* __restrict__ th = theta + n * MM * 3;

    float a0 = 0.f, a1 = 0.f, a2 = 0.f;
    #pragma unroll 8
    for (int t = 0; t < TPTS; ++t) {
        const float dx = gx - c[t*3+0];
        const float dy = gy - c[t*3+1];
        const float dz = gz - c[t*3+2];
        const float r2 = fmaf(dx,dx, fmaf(dy,dy, fmaf(dz,dz, TEPS)));  // = d2+EPS >= 0
        const float r  = sqrtf(r2);
        const float lg = __log2f(r + TEPS);        // ln2 folded into weights
        const float u  = r2 * lg;
        a0 = fmaf(u, th[t*3+0], a0);
        a1 = fmaf(u, th[t*3+1], a1);
        a2 = fmaf(u, th[t*3+2], a2);
    }
    const float* aa = th + TPTS*3;                 // affine rows [4][3]
    a0 = fmaf(gz, aa[9],  fmaf(gy, aa[6], fmaf(gx, aa[3], a0 + aa[0])));
    a1 = fmaf(gz, aa[10], fmaf(gy, aa[7], fmaf(gx, aa[4], a1 + aa[1])));
    a2 = fmaf(gz, aa[11], fmaf(gy, aa[8], fmaf(gx, aa[5], a2 + aa[2])));

    const long pid = (long)b * 256 + threadIdx.x;
    out[pid*3+0] = a0;
    out[pid*3+1] = a1;
    out[pid*3+2] = a2;
}

extern "C" void kernel_launch(void* const* d_in, const int* in_sizes, int n_in,
                              void* d_out, int out_size, void* d_ws, size_t ws_size,
                              hipStream_t stream) {
    (void)n_in; (void)out_size; (void)ws_size;
    const float* pm = (const float*)d_in[0];
    const float* pf = (const float*)d_in[1];
    const float* lm = (const float*)d_in[2];
    float* outp  = (float*)d_out;
    float* theta = (float*)d_ws;                   // N*MM*3 floats scratch

    const int N = in_sizes[2];                     // 2 batches; D=H=W=64 fixed
    const size_t lds = (size_t)(MM*ST + TPTS*3*2) * sizeof(float);  // 74,880 B

    // gfx950 allows >64KB LDS per workgroup; opt-in defensively (idempotent).
    hipFuncSetAttribute(reinterpret_cast<const void*>(tps_fit),
                        hipFuncAttributeMaxDynamicSharedMemorySize, (int)lds);

    tps_fit<<<N, 256, lds, stream>>>(pm, pf, lm, theta);
    tps_eval<<<N * 1024, 256, 0, stream>>>(pf, theta, outp);
}

// Round 3
// 180.469 us; speedup vs baseline: 2.1835x; 2.1835x over previous
//
#include <hip/hip_runtime.h>

#define TPTS 128          // control points T
#define MM   132          // T + DIM + 1
#define ST   136          // row stride in floats (34 float4)
#define NC4  34           // ST/4
#define TEPS 1e-6f
#define LN2F 0.6931471805599453f

__device__ __forceinline__ float rdlanef(float v, int l) {
    return __int_as_float(__builtin_amdgcn_readlane(__float_as_int(v), l));
}
__device__ __forceinline__ unsigned umaxu(unsigned a, unsigned b) { return a > b ? a : b; }

// wave64 max-reduce of a u32 key: 4 DPP row_shr steps + 4 readlanes (uniform result)
__device__ __forceinline__ unsigned wred_max64(unsigned k) {
    k = umaxu(k, (unsigned)__builtin_amdgcn_update_dpp(0, (int)k, 0x111, 0xF, 0xF, true));
    k = umaxu(k, (unsigned)__builtin_amdgcn_update_dpp(0, (int)k, 0x112, 0xF, 0xF, true));
    k = umaxu(k, (unsigned)__builtin_amdgcn_update_dpp(0, (int)k, 0x114, 0xF, 0xF, true));
    k = umaxu(k, (unsigned)__builtin_amdgcn_update_dpp(0, (int)k, 0x118, 0xF, 0xF, true));
    unsigned r0 = (unsigned)__builtin_amdgcn_readlane((int)k, 15);
    unsigned r1 = (unsigned)__builtin_amdgcn_readlane((int)k, 31);
    unsigned r2 = (unsigned)__builtin_amdgcn_readlane((int)k, 47);
    unsigned r3 = (unsigned)__builtin_amdgcn_readlane((int)k, 63);
    return umaxu(umaxu(r0, r1), umaxu(r2, r3));
}

// ---------------- Fit: blocked LU (KB=8) with register panels ----------------
__global__ __launch_bounds__(256) void tps_fit(
    const float* __restrict__ pm,   // targets  [N][T][3]
    const float* __restrict__ pf,   // control  [N][T][3]
    const float* __restrict__ lmb,  // lambda   [N]
    float* __restrict__ theta)      // out [N][MM][3]; rows<T pre-scaled by ln2
{
    extern __shared__ float smem[];
    float*  Mf    = smem;                         // [132][136]
    float4* M4    = reinterpret_cast<float4*>(smem);
    float*  invd  = smem + MM * ST;               // [132] (+pad)
    int*    ipivS = (int*)(smem + MM * ST + 136); // [8]
    float*  sc    = smem + MM * ST + 136 + 8;     // [128*3]
    float*  sg    = sc + TPTS * 3;                // [128*3]

    const int n    = blockIdx.x;
    const int tid  = threadIdx.x;
    const int wid  = tid >> 6;
    const int lane = tid & 63;

    for (int i = tid; i < TPTS * 3; i += 256) {
        sc[i] = pf[n * TPTS * 3 + i];
        sg[i] = pm[n * TPTS * 3 + i];
    }
    __syncthreads();
    const float lam = lmb[n];

    // ---- Fill augmented matrix (float4 tiles) ----
    for (int q = tid; q < MM * NC4; q += 256) {
        const int row = q / NC4;
        const int cg  = q - row * NC4;
        float vv[4];
        #pragma unroll
        for (int e = 0; e < 4; ++e) {
            const int col = cg * 4 + e;
            float v = 0.0f;
            if (col < TPTS) {
                if (row < TPTS) {
                    const float dx = sc[row*3+0] - sc[col*3+0];
                    const float dy = sc[row*3+1] - sc[col*3+1];
                    const float dz = sc[row*3+2] - sc[col*3+2];
                    const float r2 = fmaf(dx,dx, fmaf(dy,dy, fmaf(dz,dz, TEPS)));
                    const float r  = sqrtf(r2);
                    v = r2 * __logf(r + TEPS);
                    if (row == col) v += lam;
                } else {
                    const int ci = row - TPTS;
                    v = (ci == 0) ? 1.0f : sc[col*3 + ci - 1];
                }
            } else if (col < MM) {
                if (row < TPTS) {
                    const int ci = col - TPTS;
                    v = (ci == 0) ? 1.0f : sc[row*3 + ci - 1];
                }
            } else if (col < MM + 3) {
                if (row < TPTS) v = sg[row*3 + (col - MM)];
            }
            vv[e] = v;
        }
        M4[q] = make_float4(vv[0], vv[1], vv[2], vv[3]);
    }
    __syncthreads();

    // ---- Blocked LU with partial pivoting: 17 panels of width 8 ----
    for (int p = 0; p < 17; ++p) {
        const int j0 = p * 8;
        const int kb = (MM - j0 >= 8) ? 8 : (MM - j0);   // 8, last panel 4
        const int cb = j0 >> 2;

        // Phase A: wave0 factorizes the panel in registers
        if (wid == 0) {
            const int i0 = j0 + lane, i1 = i0 + 64, i2 = i0 + 128;
            float p0[8] = {0,0,0,0,0,0,0,0};
            float p1[8] = {0,0,0,0,0,0,0,0};
            float p2[8] = {0,0,0,0,0,0,0,0};
            if (i0 < MM) {
                float4 a = M4[i0*NC4+cb], b = M4[i0*NC4+cb+1];
                p0[0]=a.x; p0[1]=a.y; p0[2]=a.z; p0[3]=a.w;
                p0[4]=b.x; p0[5]=b.y; p0[6]=b.z; p0[7]=b.w;
            }
            if (i1 < MM) {
                float4 a = M4[i1*NC4+cb], b = M4[i1*NC4+cb+1];
                p1[0]=a.x; p1[1]=a.y; p1[2]=a.z; p1[3]=a.w;
                p1[4]=b.x; p1[5]=b.y; p1[6]=b.z; p1[7]=b.w;
            }
            if (i2 < MM) {
                float4 a = M4[i2*NC4+cb], b = M4[i2*NC4+cb+1];
                p2[0]=a.x; p2[1]=a.y; p2[2]=a.z; p2[3]=a.w;
                p2[4]=b.x; p2[5]=b.y; p2[6]=b.z; p2[7]=b.w;
            }
            #pragma unroll
            for (int k = 0; k < 8; ++k) {
                if (k < kb) {
                    // pivot search: key = |v| bits (top 24) | local row (8)
                    unsigned key = 0u;
                    if (i0 < MM && lane >= k)
                        key = umaxu(key, (__float_as_uint(fabsf(p0[k])) & 0xFFFFFF00u) | (unsigned)lane);
                    if (i1 < MM)
                        key = umaxu(key, (__float_as_uint(fabsf(p1[k])) & 0xFFFFFF00u) | (unsigned)(lane + 64));
                    if (i2 < MM)
                        key = umaxu(key, (__float_as_uint(fabsf(p2[k])) & 0xFFFFFF00u) | (unsigned)(lane + 128));
                    const unsigned km = wred_max64(key);       // uniform
                    const int piv = (int)(km & 0xFFu);         // local row of pivot
                    const int pl  = piv & 63, prg = piv >> 6;
                    float uu[8], oj[8];
                    #pragma unroll
                    for (int c = 0; c < 8; ++c) {
                        const float vsel = (prg == 0) ? p0[c] : (prg == 1) ? p1[c] : p2[c];
                        uu[c] = rdlanef(vsel, pl);             // new row-k (pivot row)
                        oj[c] = rdlanef(p0[c], k);             // old row-k
                    }
                    const bool wlk  = (lane == k);
                    const bool wswp = (lane == pl);
                    #pragma unroll
                    for (int c = 0; c < 8; ++c) {
                        if (wlk) p0[c] = uu[c];
                        if (wswp && prg == 0 && pl != k) p0[c] = oj[c];
                        if (wswp && prg == 1) p1[c] = oj[c];
                        if (wswp && prg == 2) p2[c] = oj[c];
                    }
                    if (lane == 0) ipivS[k] = j0 + piv;
                    const float pinv = 1.0f / uu[k];
                    if (i0 < MM && lane > k) {
                        p0[k] *= pinv;
                        #pragma unroll
                        for (int c = 0; c < 8; ++c) if (c > k) p0[c] = fmaf(-p0[k], uu[c], p0[c]);
                    }
                    if (i1 < MM) {
                        p1[k] *= pinv;
                        #pragma unroll
                        for (int c = 0; c < 8; ++c) if (c > k) p1[c] = fmaf(-p1[k], uu[c], p1[c]);
                    }
                    if (i2 < MM) {
                        p2[k] *= pinv;
                        #pragma unroll
                        for (int c = 0; c < 8; ++c) if (c > k) p2[c] = fmaf(-p2[k], uu[c], p2[c]);
                    }
                }
            }
            if (i0 < MM) {
                M4[i0*NC4+cb]   = make_float4(p0[0],p0[1],p0[2],p0[3]);
                M4[i0*NC4+cb+1] = make_float4(p0[4],p0[5],p0[6],p0[7]);
            }
            if (i1 < MM) {
                M4[i1*NC4+cb]   = make_float4(p1[0],p1[1],p1[2],p1[3]);
                M4[i1*NC4+cb+1] = make_float4(p1[4],p1[5],p1[6],p1[7]);
            }
            if (i2 < MM) {
                M4[i2*NC4+cb]   = make_float4(p2[0],p2[1],p2[2],p2[3]);
                M4[i2*NC4+cb+1] = make_float4(p2[4],p2[5],p2[6],p2[7]);
            }
        }
        __syncthreads();

        const int cg0 = (j0 + 8) >> 2;
        const int ncg = NC4 - cg0;            // 0 on last panel
        if (ncg > 0) {
            // Phase B: apply the panel's row swaps to trailing cols (permutation gather)
            const int nsl   = 2 * kb;
            const int npair = nsl * ncg;
            float4 gv[2]; int gidx[2]; bool gok[2];
            #pragma unroll
            for (int h = 0; h < 2; ++h) {
                const int q = tid + h * 256;
                gok[h] = (q < npair);
                if (gok[h]) {
                    const int s   = q / ncg;
                    const int cgi = q - s * ncg;
                    const int dst = (s < kb) ? (j0 + s) : ipivS[s - kb];
                    int pos = dst;
                    #pragma unroll
                    for (int k2 = 7; k2 >= 0; --k2) {
                        if (k2 < kb) {
                            const int jk = j0 + k2, pk = ipivS[k2];
                            pos = (pos == jk) ? pk : (pos == pk) ? jk : pos;
                        }
                    }
                    gidx[h] = dst * NC4 + cg0 + cgi;
                    gv[h]   = M4[pos * NC4 + cg0 + cgi];
                }
            }
            __syncthreads();
            #pragma unroll
            for (int h = 0; h < 2; ++h) if (gok[h]) M4[gidx[h]] = gv[h];
            __syncthreads();

            // Phase B2: TRSM the 8-row U-strip (unit-lower solve), one thread per col-group
            if (tid < ncg) {
                const int cg = cg0 + tid;
                float4 s[8]; float lv[8][8];
                #pragma unroll
                for (int m = 0; m < 8; ++m) {
                    s[m] = M4[(j0+m)*NC4 + cg];
                    float4 a = M4[(j0+m)*NC4 + cb], b = M4[(j0+m)*NC4 + cb + 1];
                    lv[m][0]=a.x; lv[m][1]=a.y; lv[m][2]=a.z; lv[m][3]=a.w;
                    lv[m][4]=b.x; lv[m][5]=b.y; lv[m][6]=b.z; lv[m][7]=b.w;
                }
                #pragma unroll
                for (int k2 = 0; k2 < 7; ++k2) {
                    #pragma unroll
                    for (int m = 0; m < 8; ++m) {
                        if (m > k2) {
                            s[m].x = fmaf(-lv[m][k2], s[k2].x, s[m].x);
                            s[m].y = fmaf(-lv[m][k2], s[k2].y, s[m].y);
                            s[m].z = fmaf(-lv[m][k2], s[k2].z, s[m].z);
                            s[m].w = fmaf(-lv[m][k2], s[k2].w, s[m].w);
                        }
                    }
                }
                #pragma unroll
                for (int m = 0; m < 8; ++m) M4[(j0+m)*NC4 + cg] = s[m];
            }
            __syncthreads();

            // Phase C: rank-8 trailing update, fixed col-group per thread
            const int tcg  = tid % ncg;
            const int trow = tid / ncg;
            const int nthr = 256 / ncg;
            if (trow < nthr) {
                const int cg = cg0 + tcg;
                float4 u[8];
                #pragma unroll
                for (int m = 0; m < 8; ++m) u[m] = M4[(j0+m)*NC4 + cg];
                for (int i = j0 + 8 + trow; i < MM; i += nthr) {
                    const float4 la = M4[i*NC4 + cb];
                    const float4 lb = M4[i*NC4 + cb + 1];
                    const float lc[8] = {la.x,la.y,la.z,la.w,lb.x,lb.y,lb.z,lb.w};
                    float4 acc = M4[i*NC4 + cg];
                    #pragma unroll
                    for (int m = 0; m < 8; ++m) {
                        acc.x = fmaf(-lc[m], u[m].x, acc.x);
                        acc.y = fmaf(-lc[m], u[m].y, acc.y);
                        acc.z = fmaf(-lc[m], u[m].z, acc.z);
                        acc.w = fmaf(-lc[m], u[m].w, acc.w);
                    }
                    M4[i*NC4 + cg] = acc;
                }
            }
            __syncthreads();
        }
    }

    // ---- reciprocal diagonal ----
    if (tid < MM) invd[tid] = 1.0f / Mf[tid*ST + tid];
    __syncthreads();

    // ---- Back-substitution (wave0), rows in registers ----
    if (wid == 0) {
        const int i0 = lane, i1 = lane + 64, i2 = lane + 128;
        float b0x,b0y,b0z, b1x,b1y,b1z, b2x=0,b2y=0,b2z=0;
        { float4 f = M4[i0*NC4 + 33]; b0x=f.x; b0y=f.y; b0z=f.z; }
        { float4 f = M4[i1*NC4 + 33]; b1x=f.x; b1y=f.y; b1z=f.z; }
        if (i2 < MM) { float4 f = M4[i2*NC4 + 33]; b2x=f.x; b2y=f.y; b2z=f.z; }
        for (int j = MM - 1; j >= 0; --j) {
            const int jr = j >> 6, jl = j & 63;
            const float u0 = (i0 < j) ? Mf[i0*ST + j] : 0.0f;
            const float u1 = (i1 < j) ? Mf[i1*ST + j] : 0.0f;
            const float u2 = (i2 < j && i2 < MM) ? Mf[i2*ST + j] : 0.0f;
            const float dv = invd[j];
            float s0, s1, s2;
            if (jr == 0)      { s0 = b0x; s1 = b0y; s2 = b0z; }
            else if (jr == 1) { s0 = b1x; s1 = b1y; s2 = b1z; }
            else              { s0 = b2x; s1 = b2y; s2 = b2z; }
            const float x0 = rdlanef(s0, jl) * dv;
            const float x1 = rdlanef(s1, jl) * dv;
            const float x2 = rdlanef(s2, jl) * dv;
            if (i0 < j) { b0x = fmaf(-u0,x0,b0x); b0y = fmaf(-u0,x1,b0y); b0z = fmaf(-u0,x2,b0z); }
            if (i1 < j) { b1x = fmaf(-u1,x0,b1x); b1y = fmaf(-u1,x1,b1y); b1z = fmaf(-u1,x2,b1z); }
            if (i2 < j && i2 < MM) { b2x = fmaf(-u2,x0,b2x); b2y = fmaf(-u2,x1,b2y); b2z = fmaf(-u2,x2,b2z); }
            if (lane == jl) {
                const float scale = (j < TPTS) ? LN2F : 1.0f;
                theta[n*MM*3 + j*3 + 0] = x0 * scale;
                theta[n*MM*3 + j*3 + 1] = x1 * scale;
                theta[n*MM*3 + j*3 + 2] = x2 * scale;
            }
        }
    }
}

// ---------------- Eval: z = U(r)·w + g·a over the 64^3 grid ----------------
__global__ __launch_bounds__(256) void tps_eval(
    const float* __restrict__ pf,
    const float* __restrict__ theta,
    float* __restrict__ out)
{
    const int b   = blockIdx.x;
    const int n   = b >> 10;
    const int rem = ((b & 1023) << 8) | threadIdx.x;
    const int d = rem >> 12;
    const int h = (rem >> 6) & 63;
    const int w = rem & 63;
    const float stepv = 2.0f / 63.0f;
    const float gx = fmaf((float)w, stepv, -1.0f);
    const float gy = fmaf((float)h, stepv, -1.0f);
    const float gz = fmaf((float)d, stepv, -1.0f);

    const float* __restrict__ c  = pf    + n * TPTS * 3;
    const float* __restrict__ th = theta + n * MM * 3;

    float a0 = 0.f, a1 = 0.f, a2 = 0.f;
    #pragma unroll 8
    for (int t = 0; t < TPTS; ++t) {
        const float dx = gx - c[t*3+0];
        const float dy = gy - c[t*3+1];
        const float dz = gz - c[t*3+2];
        const float r2 = fmaf(dx,dx, fmaf(dy,dy, fmaf(dz,dz, TEPS)));
        const float r  = sqrtf(r2);
        const float lg = __log2f(r + TEPS);
        const float u  = r2 * lg;
        a0 = fmaf(u, th[t*3+0], a0);
        a1 = fmaf(u, th[t*3+1], a1);
        a2 = fmaf(u, th[t*3+2], a2);
    }
    const float* aa = th + TPTS*3;
    a0 = fmaf(gz, aa[9],  fmaf(gy, aa[6], fmaf(gx, aa[3], a0 + aa[0])));
    a1 = fmaf(gz, aa[10], fmaf(gy, aa[7], fmaf(gx, aa[4], a1 + aa[1])));
    a2 = fmaf(gz, aa[11], fmaf(gy, aa[8], fmaf(gx, aa[5], a2 + aa[2])));

    const long pid = (long)b * 256 + threadIdx.x;
    out[pid*3+0] = a0;
    out[pid*3+1] = a1;
    out[pid*3+2] = a2;
}

extern "C" void kernel_launch(void* const* d_in, const int* in_sizes, int n_in,
                              void* d_out, int out_size, void* d_ws, size_t ws_size,
                              hipStream_t stream) {
    (void)n_in; (void)out_size; (void)ws_size;
    const float* pm = (const float*)d_in[0];
    const float* pf = (const float*)d_in[1];
    const float* lm = (const float*)d_in[2];
    float* outp  = (float*)d_out;
    float* theta = (float*)d_ws;

    const int N = in_sizes[2];
    const size_t lds = (size_t)(MM*ST + 136 + 8 + TPTS*3*2) * sizeof(float); // ~75.5 KB

    (void)hipFuncSetAttribute(reinterpret_cast<const void*>(tps_fit),
                              hipFuncAttributeMaxDynamicSharedMemorySize, (int)lds);

    tps_fit<<<N, 256, lds, stream>>>(pm, pf, lm, theta);
    tps_eval<<<N * 1024, 256, 0, stream>>>(pf, theta, outp);
}

// Round 4
// 165.316 us; speedup vs baseline: 2.3836x; 1.0917x over previous
//
#include <hip/hip_runtime.h>

#define TPTS 128          // control points T
#define MM   132          // T + DIM + 1
#define ST   136          // row stride in floats (34 float4)
#define NC4  34           // ST/4
#define NT   512          // fit block threads (8 waves)
#define TEPS 1e-6f
#define LN2F 0.6931471805599453f

__device__ __forceinline__ float rdlanef(float v, int l) {
    return __int_as_float(__builtin_amdgcn_readlane(__float_as_int(v), l));
}
__device__ __forceinline__ unsigned umaxu(unsigned a, unsigned b) { return a > b ? a : b; }

// wave64 max-reduce of a u32 key: 4 DPP row_shr steps + 4 readlanes (uniform result)
__device__ __forceinline__ unsigned wred_max64(unsigned k) {
    k = umaxu(k, (unsigned)__builtin_amdgcn_update_dpp(0, (int)k, 0x111, 0xF, 0xF, true));
    k = umaxu(k, (unsigned)__builtin_amdgcn_update_dpp(0, (int)k, 0x112, 0xF, 0xF, true));
    k = umaxu(k, (unsigned)__builtin_amdgcn_update_dpp(0, (int)k, 0x114, 0xF, 0xF, true));
    k = umaxu(k, (unsigned)__builtin_amdgcn_update_dpp(0, (int)k, 0x118, 0xF, 0xF, true));
    unsigned r0 = (unsigned)__builtin_amdgcn_readlane((int)k, 15);
    unsigned r1 = (unsigned)__builtin_amdgcn_readlane((int)k, 31);
    unsigned r2 = (unsigned)__builtin_amdgcn_readlane((int)k, 47);
    unsigned r3 = (unsigned)__builtin_amdgcn_readlane((int)k, 63);
    return umaxu(umaxu(r0, r1), umaxu(r2, r3));
}

// ---------------- Fit: blocked LU (KB=8) with register panels ----------------
__global__ __launch_bounds__(NT) void tps_fit(
    const float* __restrict__ pm,   // targets  [N][T][3]
    const float* __restrict__ pf,   // control  [N][T][3]
    const float* __restrict__ lmb,  // lambda   [N]
    float* __restrict__ theta)      // out [N][MM][3]; rows<T pre-scaled by ln2
{
    extern __shared__ float smem[];
    float*  Mf    = smem;                         // [132][136]
    float4* M4    = reinterpret_cast<float4*>(smem);
    float*  invd  = smem + MM * ST;               // [132] (+pad)
    int*    ipivS = (int*)(smem + MM * ST + 136); // [8]
    float*  sc    = smem + MM * ST + 136 + 8;     // [128*3]
    float*  sg    = sc + TPTS * 3;                // [128*3]

    const int n    = blockIdx.x;
    const int tid  = threadIdx.x;
    const int wid  = tid >> 6;
    const int lane = tid & 63;

    for (int i = tid; i < TPTS * 3; i += NT) {
        sc[i] = pf[n * TPTS * 3 + i];
        sg[i] = pm[n * TPTS * 3 + i];
    }
    __syncthreads();
    const float lam = lmb[n];

    // ---- Fill augmented matrix (float4 tiles) ----
    for (int q = tid; q < MM * NC4; q += NT) {
        const int row = q / NC4;
        const int cg  = q - row * NC4;
        float vv[4];
        #pragma unroll
        for (int e = 0; e < 4; ++e) {
            const int col = cg * 4 + e;
            float v = 0.0f;
            if (col < TPTS) {
                if (row < TPTS) {
                    const float dx = sc[row*3+0] - sc[col*3+0];
                    const float dy = sc[row*3+1] - sc[col*3+1];
                    const float dz = sc[row*3+2] - sc[col*3+2];
                    const float r2 = fmaf(dx,dx, fmaf(dy,dy, fmaf(dz,dz, TEPS)));
                    const float r  = sqrtf(r2);
                    v = r2 * __logf(r + TEPS);
                    if (row == col) v += lam;
                } else {
                    const int ci = row - TPTS;
                    v = (ci == 0) ? 1.0f : sc[col*3 + ci - 1];
                }
            } else if (col < MM) {
                if (row < TPTS) {
                    const int ci = col - TPTS;
                    v = (ci == 0) ? 1.0f : sc[row*3 + ci - 1];
                }
            } else if (col < MM + 3) {
                if (row < TPTS) v = sg[row*3 + (col - MM)];
            }
            vv[e] = v;
        }
        M4[q] = make_float4(vv[0], vv[1], vv[2], vv[3]);
    }
    __syncthreads();

    // ---- Blocked LU with partial pivoting: 17 panels of width 8 ----
    for (int p = 0; p < 17; ++p) {
        const int j0 = p * 8;
        const int kb = (MM - j0 >= 8) ? 8 : (MM - j0);   // 8, last panel 4
        const int cb = j0 >> 2;

        // Phase A: wave0 factorizes the panel in registers
        if (wid == 0) {
            const int i0 = j0 + lane, i1 = i0 + 64, i2 = i0 + 128;
            float p0[8] = {0,0,0,0,0,0,0,0};
            float p1[8] = {0,0,0,0,0,0,0,0};
            float p2[8] = {0,0,0,0,0,0,0,0};
            if (i0 < MM) {
                float4 a = M4[i0*NC4+cb], b = M4[i0*NC4+cb+1];
                p0[0]=a.x; p0[1]=a.y; p0[2]=a.z; p0[3]=a.w;
                p0[4]=b.x; p0[5]=b.y; p0[6]=b.z; p0[7]=b.w;
            }
            if (i1 < MM) {
                float4 a = M4[i1*NC4+cb], b = M4[i1*NC4+cb+1];
                p1[0]=a.x; p1[1]=a.y; p1[2]=a.z; p1[3]=a.w;
                p1[4]=b.x; p1[5]=b.y; p1[6]=b.z; p1[7]=b.w;
            }
            if (i2 < MM) {
                float4 a = M4[i2*NC4+cb], b = M4[i2*NC4+cb+1];
                p2[0]=a.x; p2[1]=a.y; p2[2]=a.z; p2[3]=a.w;
                p2[4]=b.x; p2[5]=b.y; p2[6]=b.z; p2[7]=b.w;
            }
            #pragma unroll
            for (int k = 0; k < 8; ++k) {
                if (k < kb) {
                    // pivot search: key = |v| bits (top 24) | local row (8)
                    unsigned key = 0u;
                    if (i0 < MM && lane >= k)
                        key = umaxu(key, (__float_as_uint(fabsf(p0[k])) & 0xFFFFFF00u) | (unsigned)lane);
                    if (i1 < MM)
                        key = umaxu(key, (__float_as_uint(fabsf(p1[k])) & 0xFFFFFF00u) | (unsigned)(lane + 64));
                    if (i2 < MM)
                        key = umaxu(key, (__float_as_uint(fabsf(p2[k])) & 0xFFFFFF00u) | (unsigned)(lane + 128));
                    const unsigned km = wred_max64(key);       // uniform
                    const int piv = (int)(km & 0xFFu);         // local row of pivot
                    const int pl  = piv & 63, prg = piv >> 6;
                    float uu[8], oj[8];
                    #pragma unroll
                    for (int c = 0; c < 8; ++c) {
                        const float vsel = (prg == 0) ? p0[c] : (prg == 1) ? p1[c] : p2[c];
                        uu[c] = rdlanef(vsel, pl);             // new row-k (pivot row)
                        oj[c] = rdlanef(p0[c], k);             // old row-k
                    }
                    const bool wlk  = (lane == k);
                    const bool wswp = (lane == pl);
                    #pragma unroll
                    for (int c = 0; c < 8; ++c) {
                        if (wlk) p0[c] = uu[c];
                        if (wswp && prg == 0 && pl != k) p0[c] = oj[c];
                        if (wswp && prg == 1) p1[c] = oj[c];
                        if (wswp && prg == 2) p2[c] = oj[c];
                    }
                    if (lane == 0) ipivS[k] = j0 + piv;
                    const float pinv = 1.0f / uu[k];
                    if (i0 < MM && lane > k) {
                        p0[k] *= pinv;
                        #pragma unroll
                        for (int c = 0; c < 8; ++c) if (c > k) p0[c] = fmaf(-p0[k], uu[c], p0[c]);
                    }
                    if (i1 < MM) {
                        p1[k] *= pinv;
                        #pragma unroll
                        for (int c = 0; c < 8; ++c) if (c > k) p1[c] = fmaf(-p1[k], uu[c], p1[c]);
                    }
                    if (i2 < MM) {
                        p2[k] *= pinv;
                        #pragma unroll
                        for (int c = 0; c < 8; ++c) if (c > k) p2[c] = fmaf(-p2[k], uu[c], p2[c]);
                    }
                }
            }
            if (i0 < MM) {
                M4[i0*NC4+cb]   = make_float4(p0[0],p0[1],p0[2],p0[3]);
                M4[i0*NC4+cb+1] = make_float4(p0[4],p0[5],p0[6],p0[7]);
            }
            if (i1 < MM) {
                M4[i1*NC4+cb]   = make_float4(p1[0],p1[1],p1[2],p1[3]);
                M4[i1*NC4+cb+1] = make_float4(p1[4],p1[5],p1[6],p1[7]);
            }
            if (i2 < MM) {
                M4[i2*NC4+cb]   = make_float4(p2[0],p2[1],p2[2],p2[3]);
                M4[i2*NC4+cb+1] = make_float4(p2[4],p2[5],p2[6],p2[7]);
            }
        }
        __syncthreads();

        const int cg0 = (j0 + 8) >> 2;
        const int ncg = NC4 - cg0;            // 32,30,...,2, then 0 on last panel
        if (ncg > 0) {
            // Phase B: apply the panel's row swaps to trailing cols (permutation gather)
            const int npair = 2 * kb * ncg;   // <= 512
            float4 gv; int gidx;
            const bool gok = (tid < npair);
            if (gok) {
                const int s   = tid / ncg;
                const int cgi = tid - s * ncg;
                const int dst = (s < kb) ? (j0 + s) : ipivS[s - kb];
                int pos = dst;
                #pragma unroll
                for (int k2 = 7; k2 >= 0; --k2) {
                    if (k2 < kb) {
                        const int jk = j0 + k2, pk = ipivS[k2];
                        pos = (pos == jk) ? pk : (pos == pk) ? jk : pos;
                    }
                }
                gidx = dst * NC4 + cg0 + cgi;
                gv   = M4[pos * NC4 + cg0 + cgi];
            }
            __syncthreads();
            if (gok) M4[gidx] = gv;
            __syncthreads();

            // Phase B2: TRSM the 8-row U-strip (unit-lower solve), one thread per col-group
            if (tid < ncg) {
                const int cg = cg0 + tid;
                float4 s[8]; float lv[8][8];
                #pragma unroll
                for (int m = 0; m < 8; ++m) {
                    s[m] = M4[(j0+m)*NC4 + cg];
                    float4 a = M4[(j0+m)*NC4 + cb], b = M4[(j0+m)*NC4 + cb + 1];
                    lv[m][0]=a.x; lv[m][1]=a.y; lv[m][2]=a.z; lv[m][3]=a.w;
                    lv[m][4]=b.x; lv[m][5]=b.y; lv[m][6]=b.z; lv[m][7]=b.w;
                }
                #pragma unroll
                for (int k2 = 0; k2 < 7; ++k2) {
                    #pragma unroll
                    for (int m = 0; m < 8; ++m) {
                        if (m > k2) {
                            s[m].x = fmaf(-lv[m][k2], s[k2].x, s[m].x);
                            s[m].y = fmaf(-lv[m][k2], s[k2].y, s[m].y);
                            s[m].z = fmaf(-lv[m][k2], s[k2].z, s[m].z);
                            s[m].w = fmaf(-lv[m][k2], s[k2].w, s[m].w);
                        }
                    }
                }
                #pragma unroll
                for (int m = 0; m < 8; ++m) M4[(j0+m)*NC4 + cg] = s[m];
            }
            __syncthreads();

            // Phase C: rank-8 trailing update; fixed col-group per thread,
            // 2-row batches with all LDS loads issued before FMAs/stores.
            const int tpc  = NT / ncg;
            const int tcg  = tid % ncg;
            const int trow = tid / ncg;
            if (trow < tpc) {
                const int cg = cg0 + tcg;
                float4 u[8];
                #pragma unroll
                for (int m = 0; m < 8; ++m) u[m] = M4[(j0+m)*NC4 + cg];
                int i = j0 + 8 + trow;
                for (; i + tpc < MM; i += 2 * tpc) {
                    const int i2r = i + tpc;
                    const float4 la0 = M4[i  *NC4 + cb];
                    const float4 lb0 = M4[i  *NC4 + cb + 1];
                    const float4 la1 = M4[i2r*NC4 + cb];
                    const float4 lb1 = M4[i2r*NC4 + cb + 1];
                    float4 acc0 = M4[i  *NC4 + cg];
                    float4 acc1 = M4[i2r*NC4 + cg];
                    const float lc0[8] = {la0.x,la0.y,la0.z,la0.w,lb0.x,lb0.y,lb0.z,lb0.w};
                    const float lc1[8] = {la1.x,la1.y,la1.z,la1.w,lb1.x,lb1.y,lb1.z,lb1.w};
                    #pragma unroll
                    for (int m = 0; m < 8; ++m) {
                        acc0.x = fmaf(-lc0[m], u[m].x, acc0.x);
                        acc0.y = fmaf(-lc0[m], u[m].y, acc0.y);
                        acc0.z = fmaf(-lc0[m], u[m].z, acc0.z);
                        acc0.w = fmaf(-lc0[m], u[m].w, acc0.w);
                        acc1.x = fmaf(-lc1[m], u[m].x, acc1.x);
                        acc1.y = fmaf(-lc1[m], u[m].y, acc1.y);
                        acc1.z = fmaf(-lc1[m], u[m].z, acc1.z);
                        acc1.w = fmaf(-lc1[m], u[m].w, acc1.w);
                    }
                    M4[i  *NC4 + cg] = acc0;
                    M4[i2r*NC4 + cg] = acc1;
                }
                if (i < MM) {
                    const float4 la = M4[i*NC4 + cb];
                    const float4 lb = M4[i*NC4 + cb + 1];
                    float4 acc = M4[i*NC4 + cg];
                    const float lc[8] = {la.x,la.y,la.z,la.w,lb.x,lb.y,lb.z,lb.w};
                    #pragma unroll
                    for (int m = 0; m < 8; ++m) {
                        acc.x = fmaf(-lc[m], u[m].x, acc.x);
                        acc.y = fmaf(-lc[m], u[m].y, acc.y);
                        acc.z = fmaf(-lc[m], u[m].z, acc.z);
                        acc.w = fmaf(-lc[m], u[m].w, acc.w);
                    }
                    M4[i*NC4 + cg] = acc;
                }
            }
            __syncthreads();
        }
    }

    // ---- reciprocal diagonal (stride 137 mod 32 = 9 -> conflict-free) ----
    if (tid < MM) invd[tid] = 1.0f / Mf[tid*ST + tid];
    __syncthreads();

    // ---- Back-substitution (wave0), rows in registers, col-(j-1) prefetch ----
    if (wid == 0) {
        const int i0 = lane, i1 = lane + 64, i2 = lane + 128;
        float b0x,b0y,b0z, b1x,b1y,b1z, b2x=0,b2y=0,b2z=0;
        { float4 f = M4[i0*NC4 + 33]; b0x=f.x; b0y=f.y; b0z=f.z; }
        { float4 f = M4[i1*NC4 + 33]; b1x=f.x; b1y=f.y; b1z=f.z; }
        if (i2 < MM) { float4 f = M4[i2*NC4 + 33]; b2x=f.x; b2y=f.y; b2z=f.z; }
        float uc0 = Mf[i0*ST + (MM-1)];
        float uc1 = Mf[i1*ST + (MM-1)];
        float uc2 = (i2 < MM) ? Mf[i2*ST + (MM-1)] : 0.0f;
        float dvc = invd[MM-1];
        for (int j = MM - 1; j >= 0; --j) {
            float un0 = 0.f, un1 = 0.f, un2 = 0.f, dvn = 0.f;
            if (j > 0) {                       // prefetch col j-1 (hides LDS latency)
                un0 = Mf[i0*ST + j-1];
                un1 = Mf[i1*ST + j-1];
                un2 = (i2 < MM) ? Mf[i2*ST + j-1] : 0.0f;
                dvn = invd[j-1];
            }
            const int jr = j >> 6, jl = j & 63;
            float s0, s1, s2;
            if (jr == 0)      { s0 = b0x; s1 = b0y; s2 = b0z; }
            else if (jr == 1) { s0 = b1x; s1 = b1y; s2 = b1z; }
            else              { s0 = b2x; s1 = b2y; s2 = b2z; }
            const float x0 = rdlanef(s0, jl) * dvc;
            const float x1 = rdlanef(s1, jl) * dvc;
            const float x2 = rdlanef(s2, jl) * dvc;
            if (i0 < j) { b0x = fmaf(-uc0,x0,b0x); b0y = fmaf(-uc0,x1,b0y); b0z = fmaf(-uc0,x2,b0z); }
            if (i1 < j) { b1x = fmaf(-uc1,x0,b1x); b1y = fmaf(-uc1,x1,b1y); b1z = fmaf(-uc1,x2,b1z); }
            if (i2 < j && i2 < MM) { b2x = fmaf(-uc2,x0,b2x); b2y = fmaf(-uc2,x1,b2y); b2z = fmaf(-uc2,x2,b2z); }
            if (lane == jl) {
                const float scale = (j < TPTS) ? LN2F : 1.0f;
                theta[n*MM*3 + j*3 + 0] = x0 * scale;
                theta[n*MM*3 + j*3 + 1] = x1 * scale;
                theta[n*MM*3 + j*3 + 2] = x2 * scale;
            }
            uc0 = un0; uc1 = un1; uc2 = un2; dvc = dvn;
        }
    }
}

// ---------------- Eval: z = U(r)·w + g·a over the 64^3 grid ----------------
__global__ __launch_bounds__(256) void tps_eval(
    const float* __restrict__ pf,
    const float* __restrict__ theta,
    float* __restrict__ out)
{
    const int b   = blockIdx.x;
    const int n   = b >> 10;
    const int rem = ((b & 1023) << 8) | threadIdx.x;
    const int d = rem >> 12;
    const int h = (rem >> 6) & 63;
    const int w = rem & 63;
    const float stepv = 2.0f / 63.0f;
    const float gx = fmaf((float)w, stepv, -1.0f);
    const float gy = fmaf((float)h, stepv, -1.0f);
    const float gz = fmaf((float)d, stepv, -1.0f);

    const float* __restrict__ c  = pf    + n * TPTS * 3;
    const float* __restrict__ th = theta + n * MM * 3;

    float a0 = 0.f, a1 = 0.f, a2 = 0.f;
    #pragma unroll 8
    for (int t = 0; t < TPTS; ++t) {
        const float dx = gx - c[t*3+0];
        const float dy = gy - c[t*3+1];
        const float dz = gz - c[t*3+2];
        const float r2 = fmaf(dx,dx, fmaf(dy,dy, fmaf(dz,dz, TEPS)));
        const float r  = sqrtf(r2);
        const float lg = __log2f(r + TEPS);
        const float u  = r2 * lg;
        a0 = fmaf(u, th[t*3+0], a0);
        a1 = fmaf(u, th[t*3+1], a1);
        a2 = fmaf(u, th[t*3+2], a2);
    }
    const float* aa = th + TPTS*3;
    a0 = fmaf(gz, aa[9],  fmaf(gy, aa[6], fmaf(gx, aa[3], a0 + aa[0])));
    a1 = fmaf(gz, aa[10], fmaf(gy, aa[7], fmaf(gx, aa[4], a1 + aa[1])));
    a2 = fmaf(gz, aa[11], fmaf(gy, aa[8], fmaf(gx, aa[5], a2 + aa[2])));

    const long pid = (long)b * 256 + threadIdx.x;
    out[pid*3+0] = a0;
    out[pid*3+1] = a1;
    out[pid*3+2] = a2;
}

extern "C" void kernel_launch(void* const* d_in, const int* in_sizes, int n_in,
                              void* d_out, int out_size, void* d_ws, size_t ws_size,
                              hipStream_t stream) {
    (void)n_in; (void)out_size; (void)ws_size;
    const float* pm = (const float*)d_in[0];
    const float* pf = (const float*)d_in[1];
    const float* lm = (const float*)d_in[2];
    float* outp  = (float*)d_out;
    float* theta = (float*)d_ws;

    const int N = in_sizes[2];
    const size_t lds = (size_t)(MM*ST + 136 + 8 + TPTS*3*2) * sizeof(float); // ~75.5 KB

    (void)hipFuncSetAttribute(reinterpret_cast<const void*>(tps_fit),
                              hipFuncAttributeMaxDynamicSharedMemorySize, (int)lds);

    tps_fit<<<N, NT, lds, stream>>>(pm, pf, lm, theta);
    tps_eval<<<N * 1024, 256, 0, stream>>>(pf, theta, outp);
}

// Round 6
// 118.938 us; speedup vs baseline: 3.3130x; 1.3899x over previous
//
#include <hip/hip_runtime.h>

#define TPTS 128          // control points T
#define MM   132          // T + DIM + 1
#define ST   136          // row stride in floats (34 float4)
#define NC4  34           // ST/4
#define NT   512          // fit block threads (8 waves)
#define NPAN 17
#define TEPS 1e-6f
#define HLN2 0.34657359027997264f   // 0.5*ln2 (folded into TPS weights)

__device__ __forceinline__ float rdlanef(float v, int l) {
    return __int_as_float(__builtin_amdgcn_readlane(__float_as_int(v), l));
}
__device__ __forceinline__ unsigned umaxu(unsigned a, unsigned b) { return a > b ? a : b; }

// wave64 max-reduce of a u32 key: 4 DPP row_shr steps + 4 readlanes (uniform result)
__device__ __forceinline__ unsigned wred_max64(unsigned k) {
    k = umaxu(k, (unsigned)__builtin_amdgcn_update_dpp(0, (int)k, 0x111, 0xF, 0xF, true));
    k = umaxu(k, (unsigned)__builtin_amdgcn_update_dpp(0, (int)k, 0x112, 0xF, 0xF, true));
    k = umaxu(k, (unsigned)__builtin_amdgcn_update_dpp(0, (int)k, 0x114, 0xF, 0xF, true));
    k = umaxu(k, (unsigned)__builtin_amdgcn_update_dpp(0, (int)k, 0x118, 0xF, 0xF, true));
    unsigned r0 = (unsigned)__builtin_amdgcn_readlane((int)k, 15);
    unsigned r1 = (unsigned)__builtin_amdgcn_readlane((int)k, 31);
    unsigned r2 = (unsigned)__builtin_amdgcn_readlane((int)k, 47);
    unsigned r3 = (unsigned)__builtin_amdgcn_readlane((int)k, 63);
    return umaxu(umaxu(r0, r1), umaxu(r2, r3));
}

// rank-8 trailing update over col-groups [cgA, cgA+ncgs); rows with elimp[i] >= pmin.
// Strip (U) rows via ipiv8; L multipliers live in each physical row's cols [cb, cb+1].
__device__ __forceinline__ void rank8_upd(
    float4* __restrict__ M4v, const int* __restrict__ ipiv8,
    const int* __restrict__ elimp, int cgA, int ncgs,
    int t, int P, int pmin, int cb)
{
    if (ncgs <= 0) return;
    const int tpc = P / ncgs;
    const int tcg = t % ncgs, trow = t / ncgs;
    if (trow >= tpc) return;
    const int cg = cgA + tcg;
    float4 u[8];
    #pragma unroll
    for (int m = 0; m < 8; ++m) u[m] = M4v[ipiv8[m]*NC4 + cg];
    int i = trow;
    for (; i + tpc < MM; i += 2*tpc) {
        const int ib = i + tpc;
        const int f0 = elimp[i], f1 = elimp[ib];
        const float4 la0 = M4v[i *NC4 + cb], lb0 = M4v[i *NC4 + cb + 1];
        const float4 la1 = M4v[ib*NC4 + cb], lb1 = M4v[ib*NC4 + cb + 1];
        float4 a0 = M4v[i*NC4 + cg], a1 = M4v[ib*NC4 + cg];
        const float c0[8] = {la0.x,la0.y,la0.z,la0.w,lb0.x,lb0.y,lb0.z,lb0.w};
        const float c1[8] = {la1.x,la1.y,la1.z,la1.w,lb1.x,lb1.y,lb1.z,lb1.w};
        #pragma unroll
        for (int m = 0; m < 8; ++m) {
            a0.x = fmaf(-c0[m], u[m].x, a0.x); a0.y = fmaf(-c0[m], u[m].y, a0.y);
            a0.z = fmaf(-c0[m], u[m].z, a0.z); a0.w = fmaf(-c0[m], u[m].w, a0.w);
            a1.x = fmaf(-c1[m], u[m].x, a1.x); a1.y = fmaf(-c1[m], u[m].y, a1.y);
            a1.z = fmaf(-c1[m], u[m].z, a1.z); a1.w = fmaf(-c1[m], u[m].w, a1.w);
        }
        if (f0 >= pmin) M4v[i *NC4 + cg] = a0;
        if (f1 >= pmin) M4v[ib*NC4 + cg] = a1;
    }
    if (i < MM) {
        const int f0 = elimp[i];
        const float4 la = M4v[i*NC4 + cb], lb = M4v[i*NC4 + cb + 1];
        float4 a0 = M4v[i*NC4 + cg];
        const float c0[8] = {la.x,la.y,la.z,la.w,lb.x,lb.y,lb.z,lb.w};
        #pragma unroll
        for (int m = 0; m < 8; ++m) {
            a0.x = fmaf(-c0[m], u[m].x, a0.x); a0.y = fmaf(-c0[m], u[m].y, a0.y);
            a0.z = fmaf(-c0[m], u[m].z, a0.z); a0.w = fmaf(-c0[m], u[m].w, a0.w);
        }
        if (f0 >= pmin) M4v[i*NC4 + cg] = a0;
    }
}

// -------- Fit: blocked LU, pivot-by-bookkeeping, A(p) overlapped with C2(p-1) --------
__global__ __launch_bounds__(NT) void tps_fit(
    const float* __restrict__ pm,   // targets  [N][T][3]
    const float* __restrict__ pf,   // control  [N][T][3]
    const float* __restrict__ lmb,  // lambda   [N]
    float* __restrict__ theta)      // out [N][MM][3]; rows<T pre-scaled by 0.5*ln2
{
    extern __shared__ float smem[];
    float*  Mf     = smem;                          // [132][136]
    float4* M4     = reinterpret_cast<float4*>(smem);
    float*  invd   = smem + MM*ST;                  // [132]
    int*    porder = (int*)(smem + MM*ST + 132);    // [132] elimination order -> phys row
    int*    elimp  = porder + 132;                  // [132] panel at which row eliminated (999 = active)
    int*    ipivS  = elimp + 132;                   // [16] double-buffered by panel parity
    float*  sc     = (float*)(ipivS + 16);          // [128*3]
    float*  sg     = sc + TPTS*3;                   // [128*3]

    const int n    = blockIdx.x;
    const int tid  = threadIdx.x;
    const int wid  = tid >> 6;
    const int lane = tid & 63;

    for (int i = tid; i < TPTS*3; i += NT) {
        sc[i] = pf[n*TPTS*3 + i];
        sg[i] = pm[n*TPTS*3 + i];
    }
    for (int i = tid; i < MM; i += NT) elimp[i] = 999;
    __syncthreads();
    const float lam = lmb[n];

    // ---- Fill augmented matrix; U(r) = 0.5*r2*ln(r2), r2 = d^2+EPS ----
    for (int q = tid; q < MM*NC4; q += NT) {
        const int row = q / NC4;
        const int cg  = q - row*NC4;
        float vv[4];
        #pragma unroll
        for (int e = 0; e < 4; ++e) {
            const int col = cg*4 + e;
            float v = 0.0f;
            if (col < TPTS) {
                if (row < TPTS) {
                    const float dx = sc[row*3+0] - sc[col*3+0];
                    const float dy = sc[row*3+1] - sc[col*3+1];
                    const float dz = sc[row*3+2] - sc[col*3+2];
                    const float r2 = fmaf(dx,dx, fmaf(dy,dy, fmaf(dz,dz, TEPS)));
                    v = 0.5f * r2 * __logf(r2);
                    if (row == col) v += lam;
                } else {
                    const int ci = row - TPTS;
                    v = (ci == 0) ? 1.0f : sc[col*3 + ci - 1];
                }
            } else if (col < MM) {
                if (row < TPTS) {
                    const int ci = col - TPTS;
                    v = (ci == 0) ? 1.0f : sc[row*3 + ci - 1];
                }
            } else if (col < MM + 3) {
                if (row < TPTS) v = sg[row*3 + (col - MM)];
            }
            vv[e] = v;
        }
        M4[q] = make_float4(vv[0], vv[1], vv[2], vv[3]);
    }
    __syncthreads();

    for (int p = 0; p < NPAN; ++p) {
        const int j0   = p*8;
        const int kb   = (MM - j0 >= 8) ? 8 : (MM - j0);   // 8, last panel 4
        const int cb   = j0 >> 2;
        const int slot = (p & 1) * 8;

        // ---- Phase X: wave0 factorizes panel p; waves 1-7 run C2 of panel p-1 ----
        if (wid == 0) {
            const int r0 = lane, r1 = lane + 64, r2 = lane + 128;
            bool lv0 = (elimp[r0] == 999);
            bool lv1 = (elimp[r1] == 999);
            bool lv2 = (r2 < MM) ? (elimp[r2] == 999) : false;
            const bool st0 = lv0, st1 = lv1, st2 = lv2;
            float a0v[8] = {0,0,0,0,0,0,0,0};
            float a1v[8] = {0,0,0,0,0,0,0,0};
            float a2v[8] = {0,0,0,0,0,0,0,0};
            {
                float4 a = M4[r0*NC4+cb], b = M4[r0*NC4+cb+1];
                a0v[0]=a.x; a0v[1]=a.y; a0v[2]=a.z; a0v[3]=a.w;
                a0v[4]=b.x; a0v[5]=b.y; a0v[6]=b.z; a0v[7]=b.w;
            }
            {
                float4 a = M4[r1*NC4+cb], b = M4[r1*NC4+cb+1];
                a1v[0]=a.x; a1v[1]=a.y; a1v[2]=a.z; a1v[3]=a.w;
                a1v[4]=b.x; a1v[5]=b.y; a1v[6]=b.z; a1v[7]=b.w;
            }
            if (r2 < MM) {
                float4 a = M4[r2*NC4+cb], b = M4[r2*NC4+cb+1];
                a2v[0]=a.x; a2v[1]=a.y; a2v[2]=a.z; a2v[3]=a.w;
                a2v[4]=b.x; a2v[5]=b.y; a2v[6]=b.z; a2v[7]=b.w;
            }
            #pragma unroll
            for (int k = 0; k < 8; ++k) {
                if (k < kb) {
                    unsigned key = 0u;
                    if (lv0) key = umaxu(key, (__float_as_uint(fabsf(a0v[k])) & 0xFFFFFF00u) | (unsigned)r0);
                    if (lv1) key = umaxu(key, (__float_as_uint(fabsf(a1v[k])) & 0xFFFFFF00u) | (unsigned)r1);
                    if (lv2) key = umaxu(key, (__float_as_uint(fabsf(a2v[k])) & 0xFFFFFF00u) | (unsigned)r2);
                    const unsigned km = wred_max64(key);
                    const int piv = (int)(km & 0xFFu);     // physical pivot row
                    const int pl = piv & 63, prg = piv >> 6;
                    float uu[8];
                    #pragma unroll
                    for (int c = 0; c < 8; ++c) {
                        const float vsel = (prg == 0) ? a0v[c] : ((prg == 1) ? a1v[c] : a2v[c]);
                        uu[c] = rdlanef(vsel, pl);
                    }
                    if (lane == pl) {                      // freeze pivot row
                        if (prg == 0) lv0 = false;
                        else if (prg == 1) lv1 = false;
                        else lv2 = false;
                    }
                    if (lane == 0) {
                        ipivS[slot + k] = piv;
                        porder[j0 + k]  = piv;
                        elimp[piv]      = p;
                    }
                    const float pinv = __builtin_amdgcn_rcpf(uu[k]);
                    if (lv0) {
                        a0v[k] *= pinv;
                        #pragma unroll
                        for (int c = 0; c < 8; ++c) { if (c > k) a0v[c] = fmaf(-a0v[k], uu[c], a0v[c]); }
                    }
                    if (lv1) {
                        a1v[k] *= pinv;
                        #pragma unroll
                        for (int c = 0; c < 8; ++c) { if (c > k) a1v[c] = fmaf(-a1v[k], uu[c], a1v[c]); }
                    }
                    if (lv2) {
                        a2v[k] *= pinv;
                        #pragma unroll
                        for (int c = 0; c < 8; ++c) { if (c > k) a2v[c] = fmaf(-a2v[k], uu[c], a2v[c]); }
                    }
                }
            }
            if (st0) {
                M4[r0*NC4+cb]   = make_float4(a0v[0],a0v[1],a0v[2],a0v[3]);
                M4[r0*NC4+cb+1] = make_float4(a0v[4],a0v[5],a0v[6],a0v[7]);
            }
            if (st1) {
                M4[r1*NC4+cb]   = make_float4(a1v[0],a1v[1],a1v[2],a1v[3]);
                M4[r1*NC4+cb+1] = make_float4(a1v[4],a1v[5],a1v[6],a1v[7]);
            }
            if (st2) {
                M4[r2*NC4+cb]   = make_float4(a2v[0],a2v[1],a2v[2],a2v[3]);
                M4[r2*NC4+cb+1] = make_float4(a2v[4],a2v[5],a2v[6],a2v[7]);
            }
        } else if (p > 0) {
            // C2 of panel p-1: col-groups [2p+2, 33], rows with elimp >= p
            rank8_upd(M4, ipivS + ((p-1)&1)*8, elimp,
                      2*p + 2, 32 - 2*p, tid - 64, NT - 64, p, 2*(p-1));
        }
        __syncthreads();

        // ---- B2: TRSM the kb-row U-strip over trailing col-groups ----
        // cg0 = (j0+8)>>2: for the last (kb=4) panel this yields ncg=0 — its RHS
        // elimination already happened inside phase A's registers (do NOT redo it).
        {
            const int cg0 = (j0 + 8) >> 2;
            const int ncg = NC4 - cg0;
            if (tid < ncg) {
                const int cg = cg0 + tid;
                int pr[8];
                #pragma unroll
                for (int m = 0; m < 8; ++m) pr[m] = ipivS[slot + ((m < kb) ? m : 0)];
                float4 s[8]; float lw[8][8];
                #pragma unroll
                for (int m = 0; m < 8; ++m) {
                    if (m < kb) {
                        s[m] = M4[pr[m]*NC4 + cg];
                        float4 a = M4[pr[m]*NC4 + cb], b = M4[pr[m]*NC4 + cb + 1];
                        lw[m][0]=a.x; lw[m][1]=a.y; lw[m][2]=a.z; lw[m][3]=a.w;
                        lw[m][4]=b.x; lw[m][5]=b.y; lw[m][6]=b.z; lw[m][7]=b.w;
                    }
                }
                #pragma unroll
                for (int k2 = 0; k2 < 7; ++k2) {
                    #pragma unroll
                    for (int m = 0; m < 8; ++m) {
                        if (m > k2 && m < kb) {
                            s[m].x = fmaf(-lw[m][k2], s[k2].x, s[m].x);
                            s[m].y = fmaf(-lw[m][k2], s[k2].y, s[m].y);
                            s[m].z = fmaf(-lw[m][k2], s[k2].z, s[m].z);
                            s[m].w = fmaf(-lw[m][k2], s[k2].w, s[m].w);
                        }
                    }
                }
                #pragma unroll
                for (int m = 0; m < 8; ++m) { if (m < kb) M4[pr[m]*NC4 + cg] = s[m]; }
            }
        }
        __syncthreads();

        // ---- C1: rank-8 update of ONLY the next panel's col-groups ----
        if (p < NPAN - 1) {
            rank8_upd(M4, ipivS + slot, elimp,
                      2*p + 2, 2, tid, NT, p + 1, 2*p);
        }
        __syncthreads();
    }

    // ---- reciprocal diagonal (order space) ----
    if (tid < MM) invd[tid] = 1.0f / Mf[porder[tid]*ST + tid];
    __syncthreads();

    // ---- Back-substitution (wave0), porder-indirected, col-(j-1) prefetch ----
    if (wid == 0) {
        const int o0 = lane, o1 = lane + 64, o2 = lane + 128;
        const int pr0 = porder[o0];
        const int pr1 = porder[o1];
        const int pr2 = (o2 < MM) ? porder[o2] : 0;
        float b0x,b0y,b0z, b1x,b1y,b1z, b2x=0,b2y=0,b2z=0;
        { float4 f = M4[pr0*NC4 + 33]; b0x=f.x; b0y=f.y; b0z=f.z; }
        { float4 f = M4[pr1*NC4 + 33]; b1x=f.x; b1y=f.y; b1z=f.z; }
        if (o2 < MM) { float4 f = M4[pr2*NC4 + 33]; b2x=f.x; b2y=f.y; b2z=f.z; }
        float uc0 = Mf[pr0*ST + (MM-1)];
        float uc1 = Mf[pr1*ST + (MM-1)];
        float uc2 = (o2 < MM) ? Mf[pr2*ST + (MM-1)] : 0.0f;
        float dvc = invd[MM-1];
        for (int j = MM - 1; j >= 0; --j) {
            float un0 = 0.f, un1 = 0.f, un2 = 0.f, dvn = 0.f;
            if (j > 0) {
                un0 = Mf[pr0*ST + j-1];
                un1 = Mf[pr1*ST + j-1];
                un2 = (o2 < MM) ? Mf[pr2*ST + j-1] : 0.0f;
                dvn = invd[j-1];
            }
            const int jr = j >> 6, jl = j & 63;
            float s0, s1, s2;
            if (jr == 0)      { s0 = b0x; s1 = b0y; s2 = b0z; }
            else if (jr == 1) { s0 = b1x; s1 = b1y; s2 = b1z; }
            else              { s0 = b2x; s1 = b2y; s2 = b2z; }
            const float x0 = rdlanef(s0, jl) * dvc;
            const float x1 = rdlanef(s1, jl) * dvc;
            const float x2 = rdlanef(s2, jl) * dvc;
            if (o0 < j) { b0x = fmaf(-uc0,x0,b0x); b0y = fmaf(-uc0,x1,b0y); b0z = fmaf(-uc0,x2,b0z); }
            if (o1 < j) { b1x = fmaf(-uc1,x0,b1x); b1y = fmaf(-uc1,x1,b1y); b1z = fmaf(-uc1,x2,b1z); }
            if (o2 < j && o2 < MM) { b2x = fmaf(-uc2,x0,b2x); b2y = fmaf(-uc2,x1,b2y); b2z = fmaf(-uc2,x2,b2z); }
            if (lane == jl) {
                const float scale = (j < TPTS) ? HLN2 : 1.0f;
                theta[n*MM*3 + j*3 + 0] = x0 * scale;
                theta[n*MM*3 + j*3 + 1] = x1 * scale;
                theta[n*MM*3 + j*3 + 2] = x2 * scale;
            }
            uc0 = un0; uc1 = un1; uc2 = un2; dvc = dvn;
        }
    }
}

// ---------------- Eval: z = U(r)·w + g·a over the 64^3 grid (no sqrt) ----------------
__global__ __launch_bounds__(256) void tps_eval(
    const float* __restrict__ pf,
    const float* __restrict__ theta,
    float* __restrict__ out)
{
    const int b   = blockIdx.x;
    const int n   = b >> 10;
    const int rem = ((b & 1023) << 8) | threadIdx.x;
    const int d = rem >> 12;
    const int h = (rem >> 6) & 63;
    const int w = rem & 63;
    const float stepv = 2.0f / 63.0f;
    const float gx = fmaf((float)w, stepv, -1.0f);
    const float gy = fmaf((float)h, stepv, -1.0f);
    const float gz = fmaf((float)d, stepv, -1.0f);

    const float* __restrict__ c  = pf    + n * TPTS * 3;
    const float* __restrict__ th = theta + n * MM * 3;

    float a0 = 0.f, a1 = 0.f, a2 = 0.f;
    #pragma unroll 8
    for (int t = 0; t < TPTS; ++t) {
        const float dx = gx - c[t*3+0];
        const float dy = gy - c[t*3+1];
        const float dz = gz - c[t*3+2];
        const float r2 = fmaf(dx,dx, fmaf(dy,dy, fmaf(dz,dz, TEPS)));
        const float lg = __log2f(r2);          // 0.5*ln2 folded into weights
        const float u  = r2 * lg;
        a0 = fmaf(u, th[t*3+0], a0);
        a1 = fmaf(u, th[t*3+1], a1);
        a2 = fmaf(u, th[t*3+2], a2);
    }
    const float* aa = th + TPTS*3;
    a0 = fmaf(gz, aa[9],  fmaf(gy, aa[6], fmaf(gx, aa[3], a0 + aa[0])));
    a1 = fmaf(gz, aa[10], fmaf(gy, aa[7], fmaf(gx, aa[4], a1 + aa[1])));
    a2 = fmaf(gz, aa[11], fmaf(gy, aa[8], fmaf(gx, aa[5], a2 + aa[2])));

    const long pid = (long)b * 256 + threadIdx.x;
    out[pid*3+0] = a0;
    out[pid*3+1] = a1;
    out[pid*3+2] = a2;
}

extern "C" void kernel_launch(void* const* d_in, const int* in_sizes, int n_in,
                              void* d_out, int out_size, void* d_ws, size_t ws_size,
                              hipStream_t stream) {
    (void)n_in; (void)out_size; (void)ws_size;
    const float* pm = (const float*)d_in[0];
    const float* pf = (const float*)d_in[1];
    const float* lm = (const float*)d_in[2];
    float* outp  = (float*)d_out;
    float* theta = (float*)d_ws;

    const int N = in_sizes[2];
    // floats: M 17952 + invd 132 + sc/sg 768; ints: porder 132 + elimp 132 + ipivS 16
    const size_t lds = (size_t)(MM*ST + 132 + TPTS*3*2) * sizeof(float)
                     + (size_t)(132 + 132 + 16) * sizeof(int);   // 76,528 B

    (void)hipFuncSetAttribute(reinterpret_cast<const void*>(tps_fit),
                              hipFuncAttributeMaxDynamicSharedMemorySize, (int)lds);

    tps_fit<<<N, NT, lds, stream>>>(pm, pf, lm, theta);
    tps_eval<<<N * 1024, 256, 0, stream>>>(pf, theta, outp);
}

// Round 7
// 114.261 us; speedup vs baseline: 3.4487x; 1.0409x over previous
//
#include <hip/hip_runtime.h>

#define TPTS 128          // control points T
#define MM   132          // T + DIM + 1
#define ST   136          // row stride in floats (34 float4)
#define NC4  34           // ST/4
#define NT   512          // fit block threads (8 waves)
#define NPAN 17
#define TEPS 1e-6f
#define HLN2 0.34657359027997264f   // 0.5*ln2 (folded into TPS weights)

__device__ __forceinline__ float rdlanef(float v, int l) {
    return __int_as_float(__builtin_amdgcn_readlane(__float_as_int(v), l));
}
__device__ __forceinline__ unsigned umaxu(unsigned a, unsigned b) { return a > b ? a : b; }

// wave64 max-reduce of a u32 key: 4 DPP row_shr steps + 4 readlanes (uniform result)
__device__ __forceinline__ unsigned wred_max64(unsigned k) {
    k = umaxu(k, (unsigned)__builtin_amdgcn_update_dpp(0, (int)k, 0x111, 0xF, 0xF, true));
    k = umaxu(k, (unsigned)__builtin_amdgcn_update_dpp(0, (int)k, 0x112, 0xF, 0xF, true));
    k = umaxu(k, (unsigned)__builtin_amdgcn_update_dpp(0, (int)k, 0x114, 0xF, 0xF, true));
    k = umaxu(k, (unsigned)__builtin_amdgcn_update_dpp(0, (int)k, 0x118, 0xF, 0xF, true));
    unsigned r0 = (unsigned)__builtin_amdgcn_readlane((int)k, 15);
    unsigned r1 = (unsigned)__builtin_amdgcn_readlane((int)k, 31);
    unsigned r2 = (unsigned)__builtin_amdgcn_readlane((int)k, 47);
    unsigned r3 = (unsigned)__builtin_amdgcn_readlane((int)k, 63);
    return umaxu(umaxu(r0, r1), umaxu(r2, r3));
}

__device__ __forceinline__ void flush_pend(float4* M4v, float4 (&pu)[8], int (&ppr)[8], int& pcg) {
    if (pcg >= 0) {
        #pragma unroll
        for (int m = 0; m < 8; ++m) M4v[ppr[m]*NC4 + pcg] = pu[m];
        pcg = -1;
    }
}

// Per col-group: in-register TRSM of the 8-row strip (redundant per thread; lw loads
// are wave-broadcast), DEFERRED strip store (pend regs, flushed next phase), then
// rank-8 update of rows with elimp >= pmin. Strip stays RAW in LDS this phase.
__device__ __forceinline__ void trsm_rank8(
    float4* __restrict__ M4v, const int* __restrict__ ipiv8,
    const int* __restrict__ elimp, int cgA, int ncgs,
    int t, int P, int pmin, int cbW,
    float4 (&pu)[8], int (&ppr)[8], int& pcg)
{
    if (ncgs <= 0) return;
    const int tpc = P / ncgs;
    const int tcg = t % ncgs, trow = t / ncgs;
    if (trow >= tpc) return;
    const int cg = cgA + tcg;
    int pr[8];
    #pragma unroll
    for (int m = 0; m < 8; ++m) pr[m] = ipiv8[m];
    float4 u[8]; float lw[8][8];
    #pragma unroll
    for (int m = 0; m < 8; ++m) {
        u[m] = M4v[pr[m]*NC4 + cg];
        float4 a = M4v[pr[m]*NC4 + cbW], b = M4v[pr[m]*NC4 + cbW + 1];
        lw[m][0]=a.x; lw[m][1]=a.y; lw[m][2]=a.z; lw[m][3]=a.w;
        lw[m][4]=b.x; lw[m][5]=b.y; lw[m][6]=b.z; lw[m][7]=b.w;
    }
    #pragma unroll
    for (int k2 = 0; k2 < 7; ++k2) {
        #pragma unroll
        for (int m = 0; m < 8; ++m) {
            if (m > k2) {
                u[m].x = fmaf(-lw[m][k2], u[k2].x, u[m].x);
                u[m].y = fmaf(-lw[m][k2], u[k2].y, u[m].y);
                u[m].z = fmaf(-lw[m][k2], u[k2].z, u[m].z);
                u[m].w = fmaf(-lw[m][k2], u[k2].w, u[m].w);
            }
        }
    }
    if (trow == 0) {                 // defer the strip store to the next phase
        #pragma unroll
        for (int m = 0; m < 8; ++m) { pu[m] = u[m]; ppr[m] = pr[m]; }
        pcg = cg;
    }
    int i = trow;
    for (; i + tpc < MM; i += 2*tpc) {
        const int ib = i + tpc;
        const int f0 = elimp[i], f1 = elimp[ib];
        const float4 la0 = M4v[i *NC4 + cbW], lb0 = M4v[i *NC4 + cbW + 1];
        const float4 la1 = M4v[ib*NC4 + cbW], lb1 = M4v[ib*NC4 + cbW + 1];
        float4 a0 = M4v[i*NC4 + cg], a1 = M4v[ib*NC4 + cg];
        const float c0[8] = {la0.x,la0.y,la0.z,la0.w,lb0.x,lb0.y,lb0.z,lb0.w};
        const float c1[8] = {la1.x,la1.y,la1.z,la1.w,lb1.x,lb1.y,lb1.z,lb1.w};
        #pragma unroll
        for (int m = 0; m < 8; ++m) {
            a0.x = fmaf(-c0[m], u[m].x, a0.x); a0.y = fmaf(-c0[m], u[m].y, a0.y);
            a0.z = fmaf(-c0[m], u[m].z, a0.z); a0.w = fmaf(-c0[m], u[m].w, a0.w);
            a1.x = fmaf(-c1[m], u[m].x, a1.x); a1.y = fmaf(-c1[m], u[m].y, a1.y);
            a1.z = fmaf(-c1[m], u[m].z, a1.z); a1.w = fmaf(-c1[m], u[m].w, a1.w);
        }
        if (f0 >= pmin) M4v[i *NC4 + cg] = a0;
        if (f1 >= pmin) M4v[ib*NC4 + cg] = a1;
    }
    if (i < MM) {
        const int f0 = elimp[i];
        const float4 la = M4v[i*NC4 + cbW], lb = M4v[i*NC4 + cbW + 1];
        float4 a0 = M4v[i*NC4 + cg];
        const float c0[8] = {la.x,la.y,la.z,la.w,lb.x,lb.y,lb.z,lb.w};
        #pragma unroll
        for (int m = 0; m < 8; ++m) {
            a0.x = fmaf(-c0[m], u[m].x, a0.x); a0.y = fmaf(-c0[m], u[m].y, a0.y);
            a0.z = fmaf(-c0[m], u[m].z, a0.z); a0.w = fmaf(-c0[m], u[m].w, a0.w);
        }
        if (f0 >= pmin) M4v[i*NC4 + cg] = a0;
    }
}

// -------- Fit: blocked LU, bookkept pivoting, TRSM+update hidden under panel A --------
__global__ __launch_bounds__(NT) void tps_fit(
    const float* __restrict__ pm,   // targets  [N][T][3]
    const float* __restrict__ pf,   // control  [N][T][3]
    const float* __restrict__ lmb,  // lambda   [N]
    float* __restrict__ theta)      // out [N][MM][3]; rows<T pre-scaled by 0.5*ln2
{
    extern __shared__ float smem[];
    float*  Mf     = smem;                          // [132][136]
    float4* M4     = reinterpret_cast<float4*>(smem);
    float*  invd   = smem + MM*ST;                  // [132]
    int*    porder = (int*)(smem + MM*ST + 132);    // [132]
    int*    elimp  = porder + 132;                  // [132] (999 = active)
    int*    ipivS  = elimp + 132;                   // [16] double-buffered by parity
    float*  sc     = (float*)(ipivS + 16);          // [128*3]
    float*  sg     = sc + TPTS*3;                   // [128*3]

    const int n    = blockIdx.x;
    const int tid  = threadIdx.x;
    const int wid  = tid >> 6;
    const int lane = tid & 63;

    float4 pu[8]; int ppr[8]; int pcg = -1;         // deferred strip-store state

    for (int i = tid; i < TPTS*3; i += NT) {
        sc[i] = pf[n*TPTS*3 + i];
        sg[i] = pm[n*TPTS*3 + i];
    }
    for (int i = tid; i < MM; i += NT) elimp[i] = 999;
    __syncthreads();
    const float lam = lmb[n];

    // ---- Fill augmented matrix; U(r) = 0.5*r2*ln(r2), r2 = d^2+EPS ----
    for (int q = tid; q < MM*NC4; q += NT) {
        const int row = q / NC4;
        const int cg  = q - row*NC4;
        float vv[4];
        #pragma unroll
        for (int e = 0; e < 4; ++e) {
            const int col = cg*4 + e;
            float v = 0.0f;
            if (col < TPTS) {
                if (row < TPTS) {
                    const float dx = sc[row*3+0] - sc[col*3+0];
                    const float dy = sc[row*3+1] - sc[col*3+1];
                    const float dz = sc[row*3+2] - sc[col*3+2];
                    const float r2 = fmaf(dx,dx, fmaf(dy,dy, fmaf(dz,dz, TEPS)));
                    v = 0.5f * r2 * __logf(r2);
                    if (row == col) v += lam;
                } else {
                    const int ci = row - TPTS;
                    v = (ci == 0) ? 1.0f : sc[col*3 + ci - 1];
                }
            } else if (col < MM) {
                if (row < TPTS) {
                    const int ci = col - TPTS;
                    v = (ci == 0) ? 1.0f : sc[row*3 + ci - 1];
                }
            } else if (col < MM + 3) {
                if (row < TPTS) v = sg[row*3 + (col - MM)];
            }
            vv[e] = v;
        }
        M4[q] = make_float4(vv[0], vv[1], vv[2], vv[3]);
    }
    __syncthreads();

    for (int p = 0; p < NPAN; ++p) {
        const int j0   = p*8;
        const int kb   = (MM - j0 >= 8) ? 8 : (MM - j0);   // 8, last panel 4
        const int cb   = j0 >> 2;
        const int slot = (p & 1) * 8;

        // ---- Phase X: wave0: A(p).  waves1-7: flush pend, then TRSM+rank8 of
        //      panel p-1 over cols >= 2p+2 (strip p-1 stays RAW in LDS; store deferred).
        if (wid == 0) {
            const int r0 = lane, r1 = lane + 64, r2 = lane + 128;
            bool lv0 = (elimp[r0] == 999);
            bool lv1 = (elimp[r1] == 999);
            bool lv2 = (r2 < MM) ? (elimp[r2] == 999) : false;
            const bool st0 = lv0, st1 = lv1, st2 = lv2;
            float a0v[8] = {0,0,0,0,0,0,0,0};
            float a1v[8] = {0,0,0,0,0,0,0,0};
            float a2v[8] = {0,0,0,0,0,0,0,0};
            {
                float4 a = M4[r0*NC4+cb], b = M4[r0*NC4+cb+1];
                a0v[0]=a.x; a0v[1]=a.y; a0v[2]=a.z; a0v[3]=a.w;
                a0v[4]=b.x; a0v[5]=b.y; a0v[6]=b.z; a0v[7]=b.w;
            }
            {
                float4 a = M4[r1*NC4+cb], b = M4[r1*NC4+cb+1];
                a1v[0]=a.x; a1v[1]=a.y; a1v[2]=a.z; a1v[3]=a.w;
                a1v[4]=b.x; a1v[5]=b.y; a1v[6]=b.z; a1v[7]=b.w;
            }
            if (r2 < MM) {
                float4 a = M4[r2*NC4+cb], b = M4[r2*NC4+cb+1];
                a2v[0]=a.x; a2v[1]=a.y; a2v[2]=a.z; a2v[3]=a.w;
                a2v[4]=b.x; a2v[5]=b.y; a2v[6]=b.z; a2v[7]=b.w;
            }
            #pragma unroll
            for (int k = 0; k < 8; ++k) {
                if (k < kb) {
                    unsigned key = 0u;
                    if (lv0) key = umaxu(key, (__float_as_uint(fabsf(a0v[k])) & 0xFFFFFF00u) | (unsigned)r0);
                    if (lv1) key = umaxu(key, (__float_as_uint(fabsf(a1v[k])) & 0xFFFFFF00u) | (unsigned)r1);
                    if (lv2) key = umaxu(key, (__float_as_uint(fabsf(a2v[k])) & 0xFFFFFF00u) | (unsigned)r2);
                    const unsigned km = wred_max64(key);
                    const int piv = (int)(km & 0xFFu);     // physical pivot row
                    const int pl = piv & 63, prg = piv >> 6;
                    float uu[8];
                    #pragma unroll
                    for (int c = 0; c < 8; ++c) {
                        const float vsel = (prg == 0) ? a0v[c] : ((prg == 1) ? a1v[c] : a2v[c]);
                        uu[c] = rdlanef(vsel, pl);
                    }
                    if (lane == pl) {                      // freeze pivot row
                        if (prg == 0) lv0 = false;
                        else if (prg == 1) lv1 = false;
                        else lv2 = false;
                    }
                    if (lane == 0) {
                        ipivS[slot + k] = piv;
                        porder[j0 + k]  = piv;
                        elimp[piv]      = p;
                    }
                    const float pinv = __builtin_amdgcn_rcpf(uu[k]);
                    if (lv0) {
                        a0v[k] *= pinv;
                        #pragma unroll
                        for (int c = 0; c < 8; ++c) { if (c > k) a0v[c] = fmaf(-a0v[k], uu[c], a0v[c]); }
                    }
                    if (lv1) {
                        a1v[k] *= pinv;
                        #pragma unroll
                        for (int c = 0; c < 8; ++c) { if (c > k) a1v[c] = fmaf(-a1v[k], uu[c], a1v[c]); }
                    }
                    if (lv2) {
                        a2v[k] *= pinv;
                        #pragma unroll
                        for (int c = 0; c < 8; ++c) { if (c > k) a2v[c] = fmaf(-a2v[k], uu[c], a2v[c]); }
                    }
                }
            }
            if (st0) {
                M4[r0*NC4+cb]   = make_float4(a0v[0],a0v[1],a0v[2],a0v[3]);
                M4[r0*NC4+cb+1] = make_float4(a0v[4],a0v[5],a0v[6],a0v[7]);
            }
            if (st1) {
                M4[r1*NC4+cb]   = make_float4(a1v[0],a1v[1],a1v[2],a1v[3]);
                M4[r1*NC4+cb+1] = make_float4(a1v[4],a1v[5],a1v[6],a1v[7]);
            }
            if (st2) {
                M4[r2*NC4+cb]   = make_float4(a2v[0],a2v[1],a2v[2],a2v[3]);
                M4[r2*NC4+cb+1] = make_float4(a2v[4],a2v[5],a2v[6],a2v[7]);
            }
        } else {
            flush_pend(M4, pu, ppr, pcg);                  // W1(p-1) strip (cols 2p,2p+1)
            if (p > 0) {
                trsm_rank8(M4, ipivS + ((p-1)&1)*8, elimp,
                           2*p + 2, 32 - 2*p, tid - 64, NT - 64, p, 2*(p-1),
                           pu, ppr, pcg);
            }
        }
        __syncthreads();

        // ---- Phase Y: prep next panel's cols {2p+2,2p+3}: flush W2 pend, then
        //      TRSM strip p + rank8 for those 2 col-groups (waves 1-4).
        if (p < NPAN - 1 && tid >= 64 && tid < 320) {
            flush_pend(M4, pu, ppr, pcg);                  // W2(p-1) strips (cols >= 2p+2)
            trsm_rank8(M4, ipivS + slot, elimp,
                       2*p + 2, 2, tid - 64, 256, p + 1, 2*p,
                       pu, ppr, pcg);
        }
        __syncthreads();
    }

    // ---- reciprocal diagonal (order space) ----
    if (tid < MM) invd[tid] = 1.0f / Mf[porder[tid]*ST + tid];
    __syncthreads();

    // ---- Back-substitution (wave0), porder-indirected, col-(j-1) prefetch ----
    if (wid == 0) {
        const int o0 = lane, o1 = lane + 64, o2 = lane + 128;
        const int pr0 = porder[o0];
        const int pr1 = porder[o1];
        const int pr2 = (o2 < MM) ? porder[o2] : 0;
        float b0x,b0y,b0z, b1x,b1y,b1z, b2x=0,b2y=0,b2z=0;
        { float4 f = M4[pr0*NC4 + 33]; b0x=f.x; b0y=f.y; b0z=f.z; }
        { float4 f = M4[pr1*NC4 + 33]; b1x=f.x; b1y=f.y; b1z=f.z; }
        if (o2 < MM) { float4 f = M4[pr2*NC4 + 33]; b2x=f.x; b2y=f.y; b2z=f.z; }
        float uc0 = Mf[pr0*ST + (MM-1)];
        float uc1 = Mf[pr1*ST + (MM-1)];
        float uc2 = (o2 < MM) ? Mf[pr2*ST + (MM-1)] : 0.0f;
        float dvc = invd[MM-1];
        for (int j = MM - 1; j >= 0; --j) {
            float un0 = 0.f, un1 = 0.f, un2 = 0.f, dvn = 0.f;
            if (j > 0) {
                un0 = Mf[pr0*ST + j-1];
                un1 = Mf[pr1*ST + j-1];
                un2 = (o2 < MM) ? Mf[pr2*ST + j-1] : 0.0f;
                dvn = invd[j-1];
            }
            const int jr = j >> 6, jl = j & 63;
            float s0, s1, s2;
            if (jr == 0)      { s0 = b0x; s1 = b0y; s2 = b0z; }
            else if (jr == 1) { s0 = b1x; s1 = b1y; s2 = b1z; }
            else              { s0 = b2x; s1 = b2y; s2 = b2z; }
            const float x0 = rdlanef(s0, jl) * dvc;
            const float x1 = rdlanef(s1, jl) * dvc;
            const float x2 = rdlanef(s2, jl) * dvc;
            if (o0 < j) { b0x = fmaf(-uc0,x0,b0x); b0y = fmaf(-uc0,x1,b0y); b0z = fmaf(-uc0,x2,b0z); }
            if (o1 < j) { b1x = fmaf(-uc1,x0,b1x); b1y = fmaf(-uc1,x1,b1y); b1z = fmaf(-uc1,x2,b1z); }
            if (o2 < j && o2 < MM) { b2x = fmaf(-uc2,x0,b2x); b2y = fmaf(-uc2,x1,b2y); b2z = fmaf(-uc2,x2,b2z); }
            if (lane == jl) {
                const float scale = (j < TPTS) ? HLN2 : 1.0f;
                theta[n*MM*3 + j*3 + 0] = x0 * scale;
                theta[n*MM*3 + j*3 + 1] = x1 * scale;
                theta[n*MM*3 + j*3 + 2] = x2 * scale;
            }
            uc0 = un0; uc1 = un1; uc2 = un2; dvc = dvn;
        }
    }
}

// ---------------- Eval: z = U(r)·w + g·a over the 64^3 grid (no sqrt) ----------------
__global__ __launch_bounds__(256) void tps_eval(
    const float* __restrict__ pf,
    const float* __restrict__ theta,
    float* __restrict__ out)
{
    const int b   = blockIdx.x;
    const int n   = b >> 10;
    const int rem = ((b & 1023) << 8) | threadIdx.x;
    const int d = rem >> 12;
    const int h = (rem >> 6) & 63;
    const int w = rem & 63;
    const float stepv = 2.0f / 63.0f;
    const float gx = fmaf((float)w, stepv, -1.0f);
    const float gy = fmaf((float)h, stepv, -1.0f);
    const float gz = fmaf((float)d, stepv, -1.0f);

    const float* __restrict__ c  = pf    + n * TPTS * 3;
    const float* __restrict__ th = theta + n * MM * 3;

    float a0 = 0.f, a1 = 0.f, a2 = 0.f;
    #pragma unroll 8
    for (int t = 0; t < TPTS; ++t) {
        const float dx = gx - c[t*3+0];
        const float dy = gy - c[t*3+1];
        const float dz = gz - c[t*3+2];
        const float r2 = fmaf(dx,dx, fmaf(dy,dy, fmaf(dz,dz, TEPS)));
        const float lg = __log2f(r2);          // 0.5*ln2 folded into weights
        const float u  = r2 * lg;
        a0 = fmaf(u, th[t*3+0], a0);
        a1 = fmaf(u, th[t*3+1], a1);
        a2 = fmaf(u, th[t*3+2], a2);
    }
    const float* aa = th + TPTS*3;
    a0 = fmaf(gz, aa[9],  fmaf(gy, aa[6], fmaf(gx, aa[3], a0 + aa[0])));
    a1 = fmaf(gz, aa[10], fmaf(gy, aa[7], fmaf(gx, aa[4], a1 + aa[1])));
    a2 = fmaf(gz, aa[11], fmaf(gy, aa[8], fmaf(gx, aa[5], a2 + aa[2])));

    const long pid = (long)b * 256 + threadIdx.x;
    out[pid*3+0] = a0;
    out[pid*3+1] = a1;
    out[pid*3+2] = a2;
}

extern "C" void kernel_launch(void* const* d_in, const int* in_sizes, int n_in,
                              void* d_out, int out_size, void* d_ws, size_t ws_size,
                              hipStream_t stream) {
    (void)n_in; (void)out_size; (void)ws_size;
    const float* pm = (const float*)d_in[0];
    const float* pf = (const float*)d_in[1];
    const float* lm = (const float*)d_in[2];
    float* outp  = (float*)d_out;
    float* theta = (float*)d_ws;

    const int N = in_sizes[2];
    const size_t lds = (size_t)(MM*ST + 132 + TPTS*3*2) * sizeof(float)
                     + (size_t)(132 + 132 + 16) * sizeof(int);   // 76,528 B

    (void)hipFuncSetAttribute(reinterpret_cast<const void*>(tps_fit),
                              hipFuncAttributeMaxDynamicSharedMemorySize, (int)lds);

    tps_fit<<<N, NT, lds, stream>>>(pm, pf, lm, theta);
    tps_eval<<<N * 1024, 256, 0, stream>>>(pf, theta, outp);
}